// Round 6
// baseline (292.786 us; speedup 1.0000x reference)
//
#include <hip/hip_runtime.h>
#include <cstdint>

// ---------------------------------------------------------------------------
// Causal self-attention block: qkv GEMM -> flash attention (32x32 MFMA,
// LDS-free register streaming) -> proj GEMM. bf16 MFMA, fp32 accumulate.
// B=4 S=2048 E=768 H=12 D=64.
// ---------------------------------------------------------------------------

typedef __bf16 bf16x8 __attribute__((ext_vector_type(8)));
typedef __bf16 bf16x4 __attribute__((ext_vector_type(4)));
typedef float  f32x4  __attribute__((ext_vector_type(4)));
typedef float  f32x16 __attribute__((ext_vector_type(16)));

#define MFMA16(a, b, c) __builtin_amdgcn_mfma_f32_16x16x32_bf16(a, b, c, 0, 0, 0)
#define MFMA32(a, b, c) __builtin_amdgcn_mfma_f32_32x32x16_bf16(a, b, c, 0, 0, 0)

static constexpr int Bb = 4, Ss = 2048, Ee = 768, Hh = 12, Dd = 64;
// softmax scale 1/8 folded with log2(e) so we can use raw v_exp_f32 (2^x)
#define QSCALE 0.18033688011112042f

__device__ __forceinline__ void gl2lds16(const void* g, void* l) {
  __builtin_amdgcn_global_load_lds(
      (const __attribute__((address_space(1))) void*)g,
      (__attribute__((address_space(3))) void*)l, 16, 0, 0);
}

__device__ __forceinline__ float fexp2(float x) {
#if __has_builtin(__builtin_amdgcn_exp2f)
  return __builtin_amdgcn_exp2f(x);
#else
  return exp2f(x);
#endif
}

// swap bits 2<->3: the shared MFMA k-slot permutation baked into Q/K/V layouts
__device__ __forceinline__ int swap23(int x) {
  return (x & ~12) | ((x & 4) << 1) | ((x & 8) >> 1);
}

// ---------------------------------------------------------------------------
// prep kernels
// ---------------------------------------------------------------------------
__global__ void cast_f32_bf16(const float* __restrict__ x,
                              __bf16* __restrict__ y, int n) {
  int i = (blockIdx.x * blockDim.x + threadIdx.x) * 4;
  if (i < n) {
    float4 v = *(const float4*)(x + i);
    bf16x4 o = {(__bf16)v.x, (__bf16)v.y, (__bf16)v.z, (__bf16)v.w};
    *(bf16x4*)(y + i) = o;
  }
}

__global__ void transpose_cast(const float* __restrict__ W,
                               __bf16* __restrict__ Wt, int K, int N) {
  __shared__ float t[64][65];
  const int k0 = blockIdx.y * 64, n0 = blockIdx.x * 64;
#pragma unroll
  for (int i = 0; i < 16; ++i) {
    int lin = i * 256 + threadIdx.x;
    int r = lin >> 6, c = lin & 63;
    t[r][c] = W[(size_t)(k0 + r) * N + n0 + c];
  }
  __syncthreads();
#pragma unroll
  for (int i = 0; i < 16; ++i) {
    int lin = i * 256 + threadIdx.x;
    int r = lin >> 6, c = lin & 63;
    Wt[(size_t)(n0 + r) * K + k0 + c] = (__bf16)t[c][r];
  }
}

// ---------------------------------------------------------------------------
// m97-style GEMM: C[M,N] = A[M,K] @ Bt[N,K]^T, 128x128 tile, BK=32.
// MODE 0: qkv epilogue -- bias; Q scaled by log2(e)/8; Q/K d-index permuted
//         via swap23; V^T flat [bh][d][S] with swap23 on the S (key) index.
//         (Exact epilogue proven in round 4.)
// MODE 1: proj epilogue (bias, fp32 out)
// ---------------------------------------------------------------------------
template <int MODE>
__global__ __launch_bounds__(256) void gemm_bt(
    const __bf16* __restrict__ A, const __bf16* __restrict__ Bt,
    const float* __restrict__ bias, __bf16* __restrict__ Qb,
    __bf16* __restrict__ Kb, __bf16* __restrict__ VTb,
    float* __restrict__ out, int K, int N) {
  __shared__ __align__(16) __bf16 As[128 * 32];
  __shared__ __align__(16) __bf16 Bs[128 * 32];
  const int tid = threadIdx.x;
  const int wave = tid >> 6, lane = tid & 63;
  const int quad = lane >> 4, c16 = lane & 15;
  const int m0 = blockIdx.y * 128, n0 = blockIdx.x * 128;
  const int wm = (wave >> 1) * 64, wn = (wave & 1) * 64;

  f32x4 acc[4][4] = {};

  for (int k0 = 0; k0 < K; k0 += 32) {
    __syncthreads();
#pragma unroll
    for (int i = 0; i < 2; ++i) {
      const int cb = (i * 4 + wave) * 64;
      const int c = cb + lane;
      const int row = c >> 2, kk = (c & 3) * 8;
      gl2lds16(&A[(size_t)(m0 + row) * K + k0 + kk], &As[cb * 8]);
      gl2lds16(&Bt[(size_t)(n0 + row) * K + k0 + kk], &Bs[cb * 8]);
    }
    __syncthreads();
    bf16x8 af[4], bf[4];
#pragma unroll
    for (int mi = 0; mi < 4; ++mi)
      af[mi] = *(const bf16x8*)&As[(wm + mi * 16 + c16) * 32 + quad * 8];
#pragma unroll
    for (int ni = 0; ni < 4; ++ni)
      bf[ni] = *(const bf16x8*)&Bs[(wn + ni * 16 + c16) * 32 + quad * 8];
#pragma unroll
    for (int mi = 0; mi < 4; ++mi)
#pragma unroll
      for (int ni = 0; ni < 4; ++ni)
        acc[mi][ni] = MFMA16(af[mi], bf[ni], acc[mi][ni]);
  }

#pragma unroll
  for (int mi = 0; mi < 4; ++mi) {
#pragma unroll
    for (int ni = 0; ni < 4; ++ni) {
      const int gcol = n0 + wn + ni * 16 + c16;
      const float bv = bias[gcol];
      const int growb = m0 + wm + mi * 16 + quad * 4;
      if (MODE == 0) {
        const int which = gcol / Ee;
        const int e = gcol - which * Ee;
        const int hh = e >> 6, dd = e & 63;
        const int bb = growb >> 11, ss = growb & 2047;
        const size_t bh = (size_t)(bb * Hh + hh);
        if (which == 2) {  // V^T flat [bh][d][S], swap23 on key (= round 4)
          const int ssp = swap23(ss);
          bf16x4 o;
#pragma unroll
          for (int r = 0; r < 4; ++r) o[r] = (__bf16)(acc[mi][ni][r] + bv);
          *(bf16x4*)&VTb[(bh * Dd + dd) * Ss + ssp] = o;
        } else if (which == 0) {  // Q: permuted d, prescaled
          const int ddp = swap23(dd);
#pragma unroll
          for (int r = 0; r < 4; ++r)
            Qb[(bh * Ss + ss + r) * Dd + ddp] =
                (__bf16)((acc[mi][ni][r] + bv) * QSCALE);
        } else {  // K: permuted d
          const int ddp = swap23(dd);
#pragma unroll
          for (int r = 0; r < 4; ++r)
            Kb[(bh * Ss + ss + r) * Dd + ddp] = (__bf16)(acc[mi][ni][r] + bv);
        }
      } else {
#pragma unroll
        for (int r = 0; r < 4; ++r)
          out[(size_t)(growb + r) * N + gcol] = acc[mi][ni][r] + bv;
      }
    }
  }
}

// ---------------------------------------------------------------------------
// flash attention v6: LDS-free register streaming, 32x32x16 MFMA.
// Block = 4 independent waves, strips {b, 31-b, 32+b, 63-b} (32 q each).
// No barriers, no LDS. K-tile frags are contiguous 4-KB global reads;
// V^T frags read the flat [bh][d][S] layout (d-stride 2048). Both groups of
// every diagonal tile are computed; causal mask (-30000) handles dead keys.
// S^T = K@Q^T; P^T B-frag = S^T C-regs (swap23 baked in global layouts).
// ---------------------------------------------------------------------------
__global__ __launch_bounds__(256, 2) void flash_attn(
    const __bf16* __restrict__ Qb, const __bf16* __restrict__ Kb,
    const __bf16* __restrict__ VTb, const int* __restrict__ amask,
    __bf16* __restrict__ Yb) {
  const int bid = blockIdx.x;
  const int xcd = bid & 7, j = bid >> 3;
  const int bh = xcd * 6 + (j >> 4);  // 6 (b,h) per XCD for L2 locality
  const int bidx = j & 15;
  const int b = bh / Hh, h = bh - b * Hh;
  const int tid = threadIdx.x, w = tid >> 6, lane = tid & 63;
  const int hl = lane >> 5, l31 = lane & 31;

  // strips: w=0:b, w=1:31-b, w=2:32+b, w=3:63-b  (block total uniform)
  const int s = ((w & 2) << 4) + ((w & 1) ? 31 - bidx : bidx);
  const int qg = s * 32 + l31;  // this lane's query
  const int ktmax = s >> 1;

  const __bf16* Qp = Qb + (size_t)bh * Ss * Dd;
  const __bf16* Kp = Kb + (size_t)bh * Ss * Dd;
  const __bf16* Vp = VTb + (size_t)bh * Dd * Ss;
  const int* amp = amask + b * Ss;

  // Q fragments (contiguous b128; swap23-d baked in global layout)
  bf16x8 qf[4];
#pragma unroll
  for (int wd = 0; wd < 4; ++wd)
    qf[wd] = *(const bf16x8*)&Qp[(size_t)qg * Dd + wd * 16 + hl * 8];

  // K tile fragments: rows are contiguous 128-B lines
  auto loadK = [&](int kt, bf16x8* dst) {
    const __bf16* base = Kp + (size_t)kt * 64 * Dd;
#pragma unroll
    for (int i = 0; i < 8; ++i)
      dst[i] = *(const bf16x8*)&base[((i >> 2) * 32 + l31) * 64 +
                                     (i & 3) * 16 + hl * 8];
  };
  // V^T tile fragments from flat [d][S] layout
  auto loadV = [&](int kt, bf16x8* dst) {
    const __bf16* base = Vp + (size_t)kt * 64;
#pragma unroll
    for (int i = 0; i < 8; ++i)
      dst[i] = *(const bf16x8*)&base[(size_t)((i >> 2) * 32 + l31) * Ss +
                                     (i & 3) * 16 + hl * 8];
  };

  bf16x8 kf[8], vf[8];
  loadK(0, kf);
  loadV(0, vf);

  f32x16 yacc[2] = {};  // Y^T[d = 32dt + (r&3)+8(r>>2)+4hl][q = l31]
  float m_i = -30000.f, l_i = 0.f;

  for (int kt = 0; kt <= ktmax; ++kt) {
    const int k0 = kt * 64;
    const bool last = (kt == ktmax);
    const uint64_t mball = __ballot(amp[k0 + lane] != 0);

    // S^T = K @ Q^T (C rows = keys, cols = queries)
    f32x16 sg[2] = {};
#pragma unroll
    for (int g = 0; g < 2; ++g) {
      f32x16 acc = {};
#pragma unroll
      for (int wd = 0; wd < 4; ++wd)
        acc = MFMA32(kf[g * 4 + wd], qf[wd], acc);
      sg[g] = acc;
    }
    if (!last) loadK(kt + 1, kf);  // prefetch next K tile

    // causal mask: only the diagonal-overlap tile
    if (k0 + 63 > s * 32) {
#pragma unroll
      for (int g = 0; g < 2; ++g)
#pragma unroll
        for (int r = 0; r < 16; ++r) {
          const int key = k0 + g * 32 + (r & 3) + 8 * (r >> 2) + 4 * hl;
          sg[g][r] = (key <= qg) ? sg[g][r] : -30000.f;
        }
    }
    // attention mask: wave-uniform skip when tile fully valid
    if (mball != ~0ull) {
#pragma unroll
      for (int g = 0; g < 2; ++g)
#pragma unroll
        for (int r = 0; r < 16; ++r) {
          const int kr = g * 32 + (r & 3) + 8 * (r >> 2) + 4 * hl;
          sg[g][r] = ((mball >> kr) & 1) ? sg[g][r] : -30000.f;
        }
    }

    // online softmax (log2 domain); row = lane's q; 1 cross-half shuffle
    float mx = sg[0][0];
#pragma unroll
    for (int r = 1; r < 16; ++r) mx = fmaxf(mx, sg[0][r]);
#pragma unroll
    for (int r = 0; r < 16; ++r) mx = fmaxf(mx, sg[1][r]);
    mx = fmaxf(mx, __shfl_xor(mx, 32));
    const float mnew = fmaxf(m_i, mx);
    const float alpha = fexp2(m_i - mnew);
    float rs = 0.f;
#pragma unroll
    for (int g = 0; g < 2; ++g)
#pragma unroll
      for (int r = 0; r < 16; ++r) {
        const float e = fexp2(sg[g][r] - mnew);
        sg[g][r] = e;
        rs += e;
      }
    rs += __shfl_xor(rs, 32);
    l_i = l_i * alpha + rs;
    m_i = mnew;
#pragma unroll
    for (int dt = 0; dt < 2; ++dt)
#pragma unroll
      for (int r = 0; r < 16; ++r) yacc[dt][r] *= alpha;

    // P^T B-fragments = S^T C-register groups (swap23 permutation shared)
    bf16x8 pf[4];
#pragma unroll
    for (int W = 0; W < 4; ++W) {
      bf16x8 f;
#pragma unroll
      for (int jj = 0; jj < 8; ++jj)
        f[jj] = (__bf16)sg[W >> 1][8 * (W & 1) + jj];
      pf[W] = f;
    }

    // Y^T += V^T @ P^T
#pragma unroll
    for (int dt = 0; dt < 2; ++dt)
#pragma unroll
      for (int W = 0; W < 4; ++W)
        yacc[dt] = MFMA32(vf[dt * 4 + W], pf[W], yacc[dt]);

    if (!last) loadV(kt + 1, vf);  // prefetch next V tile
  }

  // normalize; write Y [B,S,E] bf16 (unpermuted -- feeds gemm2)
  const float inv = (l_i > 0.f) ? 1.f / l_i : 0.f;
  __bf16* yrow = Yb + (size_t)(b * Ss + qg) * Ee + h * Dd;
#pragma unroll
  for (int dt = 0; dt < 2; ++dt)
#pragma unroll
    for (int sreg = 0; sreg < 4; ++sreg) {
      bf16x4 o;
#pragma unroll
      for (int r = 0; r < 4; ++r)
        o[r] = (__bf16)(yacc[dt][sreg * 4 + r] * inv);
      *(bf16x4*)&yrow[dt * 32 + sreg * 8 + hl * 4] = o;
    }
}

// ---------------------------------------------------------------------------
// launch
// ---------------------------------------------------------------------------
extern "C" void kernel_launch(void* const* d_in, const int* in_sizes, int n_in,
                              void* d_out, int out_size, void* d_ws,
                              size_t ws_size, hipStream_t stream) {
  const float* x      = (const float*)d_in[0];
  const float* W_attn = (const float*)d_in[1];
  const float* b_attn = (const float*)d_in[2];
  const float* W_proj = (const float*)d_in[3];
  const float* b_proj = (const float*)d_in[4];
  const int* att_mask = (const int*)d_in[5];
  float* out = (float*)d_out;

  char* ws = (char*)d_ws;
  __bf16* xb  = (__bf16*)(ws);              // 12,582,912  x as bf16 / later Y
  __bf16* Wat = (__bf16*)(ws + 12582912);   //  3,538,944  W_attn^T bf16
  __bf16* Wpt = (__bf16*)(ws + 16121856);   //  1,179,648  W_proj^T bf16
  __bf16* Qb  = (__bf16*)(ws + 17301504);   // Q [B,H,S,D] perm, x log2e/8
  __bf16* Kb  = (__bf16*)(ws + 29884416);   // K [B,H,S,D] perm
  __bf16* VTb = (__bf16*)(ws + 42467328);   // V^T [B,H,D,S] perm (flat)
  __bf16* Yb  = xb;

  cast_f32_bf16<<<6144, 256, 0, stream>>>(x, xb, Bb * Ss * Ee);
  transpose_cast<<<dim3(36, 12), 256, 0, stream>>>(W_attn, Wat, Ee, 3 * Ee);
  transpose_cast<<<dim3(12, 12), 256, 0, stream>>>(W_proj, Wpt, Ee, Ee);

  gemm_bt<0><<<dim3(18, 64), 256, 0, stream>>>(xb, Wat, b_attn, Qb, Kb, VTb,
                                               nullptr, Ee, 3 * Ee);
  flash_attn<<<768, 256, 0, stream>>>(Qb, Kb, VTb, att_mask, Yb);
  gemm_bt<1><<<dim3(6, 64), 256, 0, stream>>>(Yb, Wpt, b_proj, nullptr,
                                              nullptr, nullptr, out, Ee, Ee);
}

// Round 7
// 239.209 us; speedup vs baseline: 1.2240x; 1.2240x over previous
//
#include <hip/hip_runtime.h>
#include <cstdint>

// ---------------------------------------------------------------------------
// Causal self-attention block: qkv GEMM -> flash attention (32x32 MFMA,
// LDS-free register streaming, frag-linear tiled K/V) -> proj GEMM.
// bf16 MFMA, fp32 accumulate. B=4 S=2048 E=768 H=12 D=64.
// ---------------------------------------------------------------------------

typedef __bf16 bf16x8 __attribute__((ext_vector_type(8)));
typedef __bf16 bf16x4 __attribute__((ext_vector_type(4)));
typedef float  f32x4  __attribute__((ext_vector_type(4)));
typedef float  f32x16 __attribute__((ext_vector_type(16)));

#define MFMA16(a, b, c) __builtin_amdgcn_mfma_f32_16x16x32_bf16(a, b, c, 0, 0, 0)
#define MFMA32(a, b, c) __builtin_amdgcn_mfma_f32_32x32x16_bf16(a, b, c, 0, 0, 0)

static constexpr int Bb = 4, Ss = 2048, Ee = 768, Hh = 12, Dd = 64;
// softmax scale 1/8 folded with log2(e) so we can use raw v_exp_f32 (2^x)
#define QSCALE 0.18033688011112042f

__device__ __forceinline__ void gl2lds16(const void* g, void* l) {
  __builtin_amdgcn_global_load_lds(
      (const __attribute__((address_space(1))) void*)g,
      (__attribute__((address_space(3))) void*)l, 16, 0, 0);
}

__device__ __forceinline__ float fexp2(float x) {
#if __has_builtin(__builtin_amdgcn_exp2f)
  return __builtin_amdgcn_exp2f(x);
#else
  return exp2f(x);
#endif
}

// swap bits 2<->3: the shared MFMA k-slot permutation baked into Q/K/V layouts
__device__ __forceinline__ int swap23(int x) {
  return (x & ~12) | ((x & 4) << 1) | ((x & 8) >> 1);
}

// ---------------------------------------------------------------------------
// prep kernels
// ---------------------------------------------------------------------------
__global__ void cast_f32_bf16(const float* __restrict__ x,
                              __bf16* __restrict__ y, int n) {
  int i = (blockIdx.x * blockDim.x + threadIdx.x) * 4;
  if (i < n) {
    float4 v = *(const float4*)(x + i);
    bf16x4 o = {(__bf16)v.x, (__bf16)v.y, (__bf16)v.z, (__bf16)v.w};
    *(bf16x4*)(y + i) = o;
  }
}

__global__ void transpose_cast(const float* __restrict__ W,
                               __bf16* __restrict__ Wt, int K, int N) {
  __shared__ float t[64][65];
  const int k0 = blockIdx.y * 64, n0 = blockIdx.x * 64;
#pragma unroll
  for (int i = 0; i < 16; ++i) {
    int lin = i * 256 + threadIdx.x;
    int r = lin >> 6, c = lin & 63;
    t[r][c] = W[(size_t)(k0 + r) * N + n0 + c];
  }
  __syncthreads();
#pragma unroll
  for (int i = 0; i < 16; ++i) {
    int lin = i * 256 + threadIdx.x;
    int r = lin >> 6, c = lin & 63;
    Wt[(size_t)(n0 + r) * K + k0 + c] = (__bf16)t[c][r];
  }
}

// ---------------------------------------------------------------------------
// m97-style GEMM: C[M,N] = A[M,K] @ Bt[N,K]^T, 128x128 tile, BK=32.
// MODE 0: qkv epilogue -- bias; Q row-major [bh][s][swap23(d)] x log2(e)/8;
//         K and V^T written FRAG-LINEAR TILED: [bh][kt][frag 0..7][lane][8],
//         exactly the per-lane b128 fragments flash consumes (coalesced).
// MODE 1: proj epilogue (bias, fp32 out)
// ---------------------------------------------------------------------------
template <int MODE>
__global__ __launch_bounds__(256) void gemm_bt(
    const __bf16* __restrict__ A, const __bf16* __restrict__ Bt,
    const float* __restrict__ bias, __bf16* __restrict__ Qb,
    __bf16* __restrict__ Kb, __bf16* __restrict__ VTb,
    float* __restrict__ out, int K, int N) {
  __shared__ __align__(16) __bf16 As[128 * 32];
  __shared__ __align__(16) __bf16 Bs[128 * 32];
  const int tid = threadIdx.x;
  const int wave = tid >> 6, lane = tid & 63;
  const int quad = lane >> 4, c16 = lane & 15;
  const int m0 = blockIdx.y * 128, n0 = blockIdx.x * 128;
  const int wm = (wave >> 1) * 64, wn = (wave & 1) * 64;

  f32x4 acc[4][4] = {};

  for (int k0 = 0; k0 < K; k0 += 32) {
    __syncthreads();
#pragma unroll
    for (int i = 0; i < 2; ++i) {
      const int cb = (i * 4 + wave) * 64;
      const int c = cb + lane;
      const int row = c >> 2, kk = (c & 3) * 8;
      gl2lds16(&A[(size_t)(m0 + row) * K + k0 + kk], &As[cb * 8]);
      gl2lds16(&Bt[(size_t)(n0 + row) * K + k0 + kk], &Bs[cb * 8]);
    }
    __syncthreads();
    bf16x8 af[4], bf[4];
#pragma unroll
    for (int mi = 0; mi < 4; ++mi)
      af[mi] = *(const bf16x8*)&As[(wm + mi * 16 + c16) * 32 + quad * 8];
#pragma unroll
    for (int ni = 0; ni < 4; ++ni)
      bf[ni] = *(const bf16x8*)&Bs[(wn + ni * 16 + c16) * 32 + quad * 8];
#pragma unroll
    for (int mi = 0; mi < 4; ++mi)
#pragma unroll
      for (int ni = 0; ni < 4; ++ni)
        acc[mi][ni] = MFMA16(af[mi], bf[ni], acc[mi][ni]);
  }

#pragma unroll
  for (int mi = 0; mi < 4; ++mi) {
#pragma unroll
    for (int ni = 0; ni < 4; ++ni) {
      const int gcol = n0 + wn + ni * 16 + c16;
      const float bv = bias[gcol];
      const int growb = m0 + wm + mi * 16 + quad * 4;
      if (MODE == 0) {
        const int which = gcol / Ee;
        const int e = gcol - which * Ee;
        const int hh = e >> 6, dd = e & 63;
        const int bb = growb >> 11, ss = growb & 2047;  // 4-aligned, no cross
        const size_t bh = (size_t)(bb * Hh + hh);
        const int kt = ss >> 6;
        if (which == 2) {
          // V^T tiled: d -> row part, key-slot = swap23(in-tile key)
          const int ksl = swap23(ss & 63);  // 4-aligned, stays in 8-chunk
          const int fi = ((dd >> 5) << 2) | (ksl >> 4);
          const int lane0 = ((ksl >> 3) & 1) * 32 + (dd & 31);
          bf16x4 o;
#pragma unroll
          for (int r = 0; r < 4; ++r) o[r] = (__bf16)(acc[mi][ni][r] + bv);
          *(bf16x4*)&VTb[(((bh * 32 + kt) * 8 + fi) * 64 + lane0) * 8 +
                         (ksl & 7)] = o;
        } else if (which == 0) {  // Q: row-major, permuted d, prescaled
          const int ddp = swap23(dd);
#pragma unroll
          for (int r = 0; r < 4; ++r)
            Qb[(bh * Ss + ss + r) * Dd + ddp] =
                (__bf16)((acc[mi][ni][r] + bv) * QSCALE);
        } else {
          // K tiled: key -> row part, d-slot = swap23(d)
          const int ddp = swap23(dd);
          const int kin = ss & 63;
          const int fi = ((kin >> 5) << 2) | (ddp >> 4);
          const int lane0 = ((ddp >> 3) & 1) * 32 + (kin & 31);
          __bf16* kdst =
              &Kb[(((bh * 32 + kt) * 8 + fi) * 64 + lane0) * 8 + (ddp & 7)];
#pragma unroll
          for (int r = 0; r < 4; ++r)
            kdst[r * 8] = (__bf16)(acc[mi][ni][r] + bv);  // key+1 -> lane+1
        }
      } else {
#pragma unroll
        for (int r = 0; r < 4; ++r)
          out[(size_t)(growb + r) * N + gcol] = acc[mi][ni][r] + bv;
      }
    }
  }
}

// ---------------------------------------------------------------------------
// flash attention v7: LDS-free register streaming, 32x32x16 MFMA.
// Block = 4 independent waves; strip set {b, 31-b, 32+b, 63-b} ROTATED by
// (w+b)&3 so each SIMD receives a light/heavy mix (fixes SIMD imbalance).
// K/V tiles are frag-linear in global memory: every fragment load is a
// lane-contiguous 1-KB coalesced b128 (fixes TA address divergence).
// No barriers, no LDS; waves exit at their own diagonal.
// S^T = K@Q^T; P^T B-frag = S^T C-regs (swap23 baked in global layouts).
// ---------------------------------------------------------------------------
__global__ __launch_bounds__(256, 3) void flash_attn(
    const __bf16* __restrict__ Qb, const __bf16* __restrict__ Kb,
    const __bf16* __restrict__ VTb, const int* __restrict__ amask,
    __bf16* __restrict__ Yb) {
  const int bid = blockIdx.x;
  const int xcd = bid & 7, j = bid >> 3;
  const int bh = xcd * 6 + (j >> 4);  // 6 (b,h) per XCD for L2 locality
  const int bidx = j & 15;
  const int b = bh / Hh, h = bh - b * Hh;
  const int tid = threadIdx.x, w = tid >> 6, lane = tid & 63;
  const int hl = lane >> 5, l31 = lane & 31;

  // rotated strip assignment: SIMD w gets a different weight class per block
  const int wr = (w + bidx) & 3;
  const int s = ((wr & 2) << 4) + ((wr & 1) ? 31 - bidx : bidx);
  const int qg = s * 32 + l31;  // this lane's query
  const int ktmax = s >> 1;

  const __bf16* Qp = Qb + (size_t)bh * Ss * Dd;
  const __bf16* Ktl = Kb + (size_t)bh * 32 * 4096;   // 8-KB frag-linear tiles
  const __bf16* Vtl = VTb + (size_t)bh * 32 * 4096;
  const int* amp = amask + b * Ss;

  // Q fragments (contiguous b128; swap23-d baked in global layout)
  bf16x8 qf[4];
#pragma unroll
  for (int wd = 0; wd < 4; ++wd)
    qf[wd] = *(const bf16x8*)&Qp[(size_t)qg * Dd + wd * 16 + hl * 8];

  // frag-linear tile load: 8 perfectly-coalesced b128 loads
  auto loadF = [&](const __bf16* t, bf16x8* dst) {
#pragma unroll
    for (int i = 0; i < 8; ++i)
      dst[i] = *(const bf16x8*)&t[(i * 64 + lane) * 8];
  };

  bf16x8 kf[8], vf[8];
  loadF(Ktl, kf);
  loadF(Vtl, vf);

  f32x16 yacc[2] = {};  // Y^T[d = 32dt + (r&3)+8(r>>2)+4hl][q = l31]
  float m_i = -30000.f, l_i = 0.f;

  for (int kt = 0; kt <= ktmax; ++kt) {
    const int k0 = kt * 64;
    const bool last = (kt == ktmax);
    const uint64_t mball = __ballot(amp[k0 + lane] != 0);

    // S^T = K @ Q^T (C rows = keys, cols = queries)
    f32x16 sg[2];
#pragma unroll
    for (int g = 0; g < 2; ++g) {
      f32x16 acc = {};
#pragma unroll
      for (int wd = 0; wd < 4; ++wd)
        acc = MFMA32(kf[g * 4 + wd], qf[wd], acc);
      sg[g] = acc;
    }
    if (!last) loadF(Ktl + (kt + 1) * 4096, kf);  // prefetch next K tile

    // causal mask: only the diagonal-overlap tile
    if (k0 + 63 > s * 32) {
#pragma unroll
      for (int g = 0; g < 2; ++g)
#pragma unroll
        for (int r = 0; r < 16; ++r) {
          const int key = k0 + g * 32 + (r & 3) + 8 * (r >> 2) + 4 * hl;
          sg[g][r] = (key <= qg) ? sg[g][r] : -30000.f;
        }
    }
    // attention mask: wave-uniform skip when tile fully valid
    if (mball != ~0ull) {
#pragma unroll
      for (int g = 0; g < 2; ++g)
#pragma unroll
        for (int r = 0; r < 16; ++r) {
          const int kr = g * 32 + (r & 3) + 8 * (r >> 2) + 4 * hl;
          sg[g][r] = ((mball >> kr) & 1) ? sg[g][r] : -30000.f;
        }
    }

    // online softmax (log2 domain); row = lane's q; 1 cross-half shuffle
    float mx = sg[0][0];
#pragma unroll
    for (int r = 1; r < 16; ++r) mx = fmaxf(mx, sg[0][r]);
#pragma unroll
    for (int r = 0; r < 16; ++r) mx = fmaxf(mx, sg[1][r]);
    mx = fmaxf(mx, __shfl_xor(mx, 32));
    const float mnew = fmaxf(m_i, mx);
    // wave-uniform rescale skip: common case once m has stabilized
    if (!__all(mnew == m_i)) {
      const float alpha = fexp2(m_i - mnew);
      l_i *= alpha;
#pragma unroll
      for (int dt = 0; dt < 2; ++dt)
#pragma unroll
        for (int r = 0; r < 16; ++r) yacc[dt][r] *= alpha;
    }
    float rs = 0.f;
#pragma unroll
    for (int g = 0; g < 2; ++g)
#pragma unroll
      for (int r = 0; r < 16; ++r) {
        const float e = fexp2(sg[g][r] - mnew);
        sg[g][r] = e;
        rs += e;
      }
    rs += __shfl_xor(rs, 32);
    l_i += rs;
    m_i = mnew;

    // P^T B-fragments = S^T C-register groups (swap23 permutation shared)
    bf16x8 pf[4];
#pragma unroll
    for (int W = 0; W < 4; ++W) {
      bf16x8 f;
#pragma unroll
      for (int jj = 0; jj < 8; ++jj)
        f[jj] = (__bf16)sg[W >> 1][8 * (W & 1) + jj];
      pf[W] = f;
    }

    // Y^T += V^T @ P^T
#pragma unroll
    for (int dt = 0; dt < 2; ++dt)
#pragma unroll
      for (int W = 0; W < 4; ++W)
        yacc[dt] = MFMA32(vf[dt * 4 + W], pf[W], yacc[dt]);

    if (!last) loadF(Vtl + (kt + 1) * 4096, vf);  // prefetch next V tile
  }

  // normalize; write Y [B,S,E] bf16 (unpermuted -- feeds gemm2)
  const float inv = (l_i > 0.f) ? 1.f / l_i : 0.f;
  __bf16* yrow = Yb + (size_t)(b * Ss + qg) * Ee + h * Dd;
#pragma unroll
  for (int dt = 0; dt < 2; ++dt)
#pragma unroll
    for (int sreg = 0; sreg < 4; ++sreg) {
      bf16x4 o;
#pragma unroll
      for (int r = 0; r < 4; ++r)
        o[r] = (__bf16)(yacc[dt][sreg * 4 + r] * inv);
      *(bf16x4*)&yrow[dt * 32 + sreg * 8 + hl * 4] = o;
    }
}

// ---------------------------------------------------------------------------
// launch
// ---------------------------------------------------------------------------
extern "C" void kernel_launch(void* const* d_in, const int* in_sizes, int n_in,
                              void* d_out, int out_size, void* d_ws,
                              size_t ws_size, hipStream_t stream) {
  const float* x      = (const float*)d_in[0];
  const float* W_attn = (const float*)d_in[1];
  const float* b_attn = (const float*)d_in[2];
  const float* W_proj = (const float*)d_in[3];
  const float* b_proj = (const float*)d_in[4];
  const int* att_mask = (const int*)d_in[5];
  float* out = (float*)d_out;

  char* ws = (char*)d_ws;
  __bf16* xb  = (__bf16*)(ws);              // 12,582,912  x as bf16 / later Y
  __bf16* Wat = (__bf16*)(ws + 12582912);   //  3,538,944  W_attn^T bf16
  __bf16* Wpt = (__bf16*)(ws + 16121856);   //  1,179,648  W_proj^T bf16
  __bf16* Qb  = (__bf16*)(ws + 17301504);   // Q [bh][s][d'] perm, x log2e/8
  __bf16* Kb  = (__bf16*)(ws + 29884416);   // K frag-linear [bh][32][8][64][8]
  __bf16* VTb = (__bf16*)(ws + 42467328);   // V^T frag-linear tiles
  __bf16* Yb  = xb;

  cast_f32_bf16<<<6144, 256, 0, stream>>>(x, xb, Bb * Ss * Ee);
  transpose_cast<<<dim3(36, 12), 256, 0, stream>>>(W_attn, Wat, Ee, 3 * Ee);
  transpose_cast<<<dim3(12, 12), 256, 0, stream>>>(W_proj, Wpt, Ee, Ee);

  gemm_bt<0><<<dim3(18, 64), 256, 0, stream>>>(xb, Wat, b_attn, Qb, Kb, VTb,
                                               nullptr, Ee, 3 * Ee);
  flash_attn<<<768, 256, 0, stream>>>(Qb, Kb, VTb, att_mask, Yb);
  gemm_bt<1><<<dim3(6, 64), 256, 0, stream>>>(Yb, Wpt, b_proj, nullptr,
                                              nullptr, nullptr, out, Ee, Ee);
}